// Round 4
// baseline (156.656 us; speedup 1.0000x reference)
//
#include <hip/hip_runtime.h>
#include <hip/hip_bf16.h>
#include <stdint.h>

#define DIM 1024
#define T_LEN 2048
#define NB 2
#define NH 16
#define HD 64
#define NQT 32   // 2048/64 q-tiles

typedef float f32x4 __attribute__((ext_vector_type(4)));
typedef __bf16 bf16x8 __attribute__((ext_vector_type(8)));
typedef __bf16 bf16x2 __attribute__((ext_vector_type(2)));

__device__ __forceinline__ float sgnf(float v) {
    return (v > 0.f) ? 1.f : ((v < 0.f) ? -1.f : 0.f);
}

__device__ __forceinline__ float sigmoid_half(float v) {
    // sigmoid(0.5*v) = 1/(1 + 2^(-0.5*log2(e)*v))
    return __builtin_amdgcn_rcpf(1.f + __builtin_amdgcn_exp2f(-0.72134752f * v));
}

// ---------------- prepass: x(f32) -> Xb (bf16 row-major), Xt (bf16, [b][h][d][t]) ----------------
__global__ __launch_bounds__(256) void prep_kernel(
    const float* __restrict__ x, __bf16* __restrict__ xb, __bf16* __restrict__ xt)
{
    __shared__ __align__(16) __bf16 tile[64][72];

    const int bid = blockIdx.x;
    const int h = bid & 15, tmp = bid >> 4, tt = tmp & 31, b = tmp >> 5;
    const int tid = threadIdx.x;
    const int r = tid >> 2, c0 = (tid & 3) * 16;

    const size_t rowbase = ((size_t)(b * T_LEN + tt * 64 + r)) * DIM + h * HD + c0;
    const float* xp = x + rowbase;

    __bf16 v[16];
    #pragma unroll
    for (int i = 0; i < 16; i += 4) {
        f32x4 f = *(const f32x4*)(xp + i);
        #pragma unroll
        for (int j = 0; j < 4; ++j) v[i + j] = (__bf16)f[j];
    }
    bf16x8 s0, s1;
    #pragma unroll
    for (int j = 0; j < 8; ++j) { s0[j] = v[j]; s1[j] = v[8 + j]; }
    *(bf16x8*)(xb + rowbase)     = s0;
    *(bf16x8*)(xb + rowbase + 8) = s1;
    *(bf16x8*)&tile[r][c0]     = s0;
    *(bf16x8*)&tile[r][c0 + 8] = s1;

    __syncthreads();

    const int d = tid >> 2, t0c = (tid & 3) * 16;
    __bf16 ov[16];
    #pragma unroll
    for (int i = 0; i < 16; ++i) ov[i] = tile[t0c + i][d];
    bf16x8 o0, o1;
    #pragma unroll
    for (int j = 0; j < 8; ++j) { o0[j] = ov[j]; o1[j] = ov[8 + j]; }
    const size_t obase = ((size_t)((b * NH + h) * HD + d)) * T_LEN + tt * 64 + t0c;
    *(bf16x8*)(xt + obase)     = o0;
    *(bf16x8*)(xt + obase + 8) = o1;
}

// ---------------- main kernel: barrier-free, LDS-free K/V, direct global fragments ----------------
// One 64-row q-tile per block, 4 waves (16 q-rows each). All K/V fragments are
// read straight from xb/xt (L2-resident per XCD: bh in low 5 bits of bid ->
// each XCD sees only h = xcd (mod 8), working set ~2 MB < 4 MB L2/XCD).
// Heavy-first (LPT) over q-tiles; 1024 blocks -> 4 blocks/CU at <=128 VGPR.
__global__ __launch_bounds__(256, 4) void mba_main(
    const __bf16* __restrict__ xb, const __bf16* __restrict__ xt,
    const float* __restrict__ bvq, const float* __restrict__ bvk,
    const float* __restrict__ bvv, float* __restrict__ out)
{
    // per-wave P scratch only (no inter-wave sharing, no barriers)
    __shared__ __align__(16) __bf16 Pt[4][16][72];

    const int bid = blockIdx.x;
    const int qt = (NQT - 1) - (bid >> 5);   // heavy tiles dispatched first
    const int bh = bid & 31;
    const int b = bh >> 4, h = bh & 15;
    const int q0 = qt * 64;

    const int tid = threadIdx.x;
    const int w = tid >> 6, l = tid & 63, lq = l & 15, lh = l >> 4;

    const size_t xb_bh = (size_t)b * T_LEN * DIM + h * HD;      // row stride DIM
    const size_t xt_bh = (size_t)((b * NH + h) * HD) * T_LEN;   // row stride T_LEN

    // ---- Q fragments with folded sign(bvq)*sign(bvk); used as the MFMA B-operand ----
    bf16x8 qa[2];
    {
        const float* bq = bvq + h * HD;
        const float* bk = bvk + h * HD;
        #pragma unroll
        for (int ks = 0; ks < 2; ++ks) {
            const int d0 = ks * 32 + lh * 8;
            bf16x8 va = *(const bf16x8*)(xb + xb_bh + (size_t)(q0 + w * 16 + lq) * DIM + d0);
            #pragma unroll
            for (int j = 0; j < 8; ++j) {
                float f = sgnf(bq[d0 + j]) * sgnf(bk[d0 + j]);
                qa[ks][j] = (__bf16)((float)va[j] * f);
            }
        }
    }
    // V-sign for epilogue (column d = 16n+lq)
    float sv[4];
    #pragma unroll
    for (int n = 0; n < 4; ++n) sv[n] = sgnf(bvv[h * HD + n * 16 + lq]);

    f32x4 o[4];
    #pragma unroll
    for (int n = 0; n < 4; ++n) o[n] = (f32x4){0, 0, 0, 0};

    // fragment base addresses (lane-constant parts)
    const __bf16* kbase = xb + xb_bh + (size_t)lq * DIM + lh * 8;  // + (kv0+n*16)*DIM + ks*32
    const __bf16* vbase = xt + xt_bh + (size_t)lq * T_LEN + lh * 8; // + (n*16)*T_LEN + kv0 + ks*32

    for (int t = 0; t <= qt; ++t) {
        const int kv0 = t * 64;

        // ---- V fragments first (consumed last -> latency hidden by S+sigmoid) ----
        bf16x8 vf[2][4];
        #pragma unroll
        for (int ks = 0; ks < 2; ++ks)
            #pragma unroll
            for (int n = 0; n < 4; ++n)
                vf[ks][n] = *(const bf16x8*)(vbase + (size_t)(n * 16) * T_LEN + kv0 + ks * 32);

        // ---- K fragments + S^T = K Q^T ----
        // lane (lq,lh) holds S[s = n*16+lh*4+j][q = w*16+lq]
        f32x4 s[4];
        #pragma unroll
        for (int n = 0; n < 4; ++n) s[n] = (f32x4){0, 0, 0, 0};
        #pragma unroll
        for (int ks = 0; ks < 2; ++ks) {
            #pragma unroll
            for (int n = 0; n < 4; ++n) {
                bf16x8 kf = *(const bf16x8*)(kbase + (size_t)(kv0 + n * 16) * DIM + ks * 32);
                s[n] = __builtin_amdgcn_mfma_f32_16x16x32_bf16(kf, qa[ks], s[n], 0, 0, 0);
            }
        }

        // ---- sigmoid + causal mask -> packed b32 P writes (s-pairs lane-local) ----
        const bool diag = (t == qt);
        const int q_loc = w * 16 + lq;
        #pragma unroll
        for (int n = 0; n < 4; ++n) {
            #pragma unroll
            for (int hh = 0; hh < 2; ++hh) {
                const int s0 = n * 16 + lh * 4 + 2 * hh;
                float p0 = sigmoid_half(s[n][2 * hh]);
                float p1 = sigmoid_half(s[n][2 * hh + 1]);
                if (diag) {
                    if (s0 > q_loc)     p0 = 0.f;
                    if (s0 + 1 > q_loc) p1 = 0.f;
                }
                *(bf16x2*)&Pt[w][lq][s0] = (bf16x2){(__bf16)p0, (__bf16)p1};
            }
        }

        // ---- P fragments (same-wave LDS RAW: in-order DS pipe) ----
        bf16x8 pf[2];
        #pragma unroll
        for (int ks = 0; ks < 2; ++ks)
            pf[ks] = *(const bf16x8*)&Pt[w][lq][ks * 32 + lh * 8];

        // ---- O += P V ----
        #pragma unroll
        for (int ks = 0; ks < 2; ++ks)
            #pragma unroll
            for (int n = 0; n < 4; ++n)
                o[n] = __builtin_amdgcn_mfma_f32_16x16x32_bf16(pf[ks], vf[ks][n], o[n], 0, 0, 0);
    }

    // ---- epilogue: apply sign(bvv) and store ----
    float* op = out + ((size_t)(b * T_LEN + q0 + w * 16)) * DIM + h * HD;
    #pragma unroll
    for (int n = 0; n < 4; ++n) {
        #pragma unroll
        for (int j = 0; j < 4; ++j) {
            op[(size_t)(lh * 4 + j) * DIM + n * 16 + lq] = o[n][j] * sv[n];
        }
    }
}

// ---------------- fallback (round-1 kernel) if ws too small ----------------
__global__ __launch_bounds__(256) void mba_fallback(
    const float* __restrict__ x,
    const float* __restrict__ bvq,
    const float* __restrict__ bvk,
    const float* __restrict__ bvv,
    float* __restrict__ out)
{
    __shared__ __align__(16) __bf16 Kb[64][72];
    __shared__ __align__(16) __bf16 Vt[HD][72];
    __shared__ __align__(16) __bf16 Pb[4][16][72];

    const int bid = blockIdx.x;
    const int qt  = (NQT - 1) - (bid & (NQT - 1));
    const int bh  = bid >> 5;
    const int b   = bh >> 4;
    const int h   = bh & 15;

    const int tid = threadIdx.x;
    const int w   = tid >> 6;
    const int l   = tid & 63;
    const int lq  = l & 15;
    const int lh  = l >> 4;

    const int  q0    = qt * 64;
    const long xbase = ((long)b * T_LEN) * DIM + h * HD;

    bf16x8 qa[2];
    {
        const int   qrow = q0 + w * 16 + lq;
        const float* qp  = x + xbase + (long)qrow * DIM + lh * 8;
        const float* gp  = bvq + h * HD + lh * 8;
        #pragma unroll
        for (int ks = 0; ks < 2; ++ks)
            #pragma unroll
            for (int j = 0; j < 8; ++j)
                qa[ks][j] = (__bf16)(qp[ks * 32 + j] * sgnf(gp[ks * 32 + j]));
    }

    f32x4 o[4];
    #pragma unroll
    for (int n = 0; n < 4; ++n) o[n] = (f32x4){0.f, 0.f, 0.f, 0.f};

    const int r_st = tid >> 2;
    const int c0   = (tid & 3) * 16;
    const float* gk = bvk + h * HD + c0;
    const float* gv = bvv + h * HD + c0;

    for (int kvt = 0; kvt <= qt; ++kvt) {
        const int kv0 = kvt * 64;
        __syncthreads();
        {
            const float* kp = x + xbase + (long)(kv0 + r_st) * DIM + c0;
            __bf16 kb[16];
            #pragma unroll
            for (int i = 0; i < 16; ++i) kb[i] = (__bf16)(kp[i] * sgnf(gk[i]));
            *(bf16x8*)&Kb[r_st][c0]     = *(bf16x8*)&kb[0];
            *(bf16x8*)&Kb[r_st][c0 + 8] = *(bf16x8*)&kb[8];
            #pragma unroll
            for (int i = 0; i < 16; ++i)
                Vt[c0 + i][r_st] = (__bf16)(kp[i] * sgnf(gv[i]));
        }
        __syncthreads();

        f32x4 s[4];
        #pragma unroll
        for (int n = 0; n < 4; ++n) s[n] = (f32x4){0.f, 0.f, 0.f, 0.f};
        #pragma unroll
        for (int ks = 0; ks < 2; ++ks)
            #pragma unroll
            for (int n = 0; n < 4; ++n) {
                bf16x8 kf = *(const bf16x8*)&Kb[n * 16 + lq][ks * 32 + lh * 8];
                s[n] = __builtin_amdgcn_mfma_f32_16x16x32_bf16(qa[ks], kf, s[n], 0, 0, 0);
            }

        const bool diag = (kvt == qt);
        #pragma unroll
        for (int n = 0; n < 4; ++n)
            #pragma unroll
            for (int j = 0; j < 4; ++j) {
                float p = sigmoid_half(s[n][j]);
                if (diag && (n * 16 + lq) > (w * 16 + lh * 4 + j)) p = 0.f;
                Pb[w][lh * 4 + j][n * 16 + lq] = (__bf16)p;
            }

        #pragma unroll
        for (int ks = 0; ks < 2; ++ks) {
            bf16x8 pf = *(const bf16x8*)&Pb[w][lq][ks * 32 + lh * 8];
            #pragma unroll
            for (int n = 0; n < 4; ++n) {
                bf16x8 vf = *(const bf16x8*)&Vt[n * 16 + lq][ks * 32 + lh * 8];
                o[n] = __builtin_amdgcn_mfma_f32_16x16x32_bf16(pf, vf, o[n], 0, 0, 0);
            }
        }
    }

    float* op = out + ((long)b * T_LEN + q0 + w * 16) * DIM + h * HD;
    #pragma unroll
    for (int n = 0; n < 4; ++n)
        #pragma unroll
        for (int j = 0; j < 4; ++j)
            op[(long)(lh * 4 + j) * DIM + n * 16 + lq] = o[n][j];
}

extern "C" void kernel_launch(void* const* d_in, const int* in_sizes, int n_in,
                              void* d_out, int out_size, void* d_ws, size_t ws_size,
                              hipStream_t stream) {
    (void)in_sizes; (void)n_in; (void)out_size;
    const float* x   = (const float*)d_in[0];
    const float* bvq = (const float*)d_in[1];
    const float* bvk = (const float*)d_in[2];
    const float* bvv = (const float*)d_in[3];
    float* out = (float*)d_out;

    const size_t XB_BYTES = (size_t)NB * T_LEN * DIM * sizeof(__bf16);  // 8 MB
    const size_t XT_BYTES = XB_BYTES;                                    // 8 MB

    if (ws_size < XB_BYTES + XT_BYTES) {
        mba_fallback<<<NB * NH * NQT, 256, 0, stream>>>(x, bvq, bvk, bvv, out);
        return;
    }

    __bf16* xb = (__bf16*)d_ws;
    __bf16* xt = xb + (size_t)NB * T_LEN * DIM;

    prep_kernel<<<NB * NQT * NH, 256, 0, stream>>>(x, xb, xt);
    mba_main<<<NB * NH * NQT, 256, 0, stream>>>(xb, xt, bvq, bvk, bvv, out);
}

// Round 6
// 47.795 us; speedup vs baseline: 3.2777x; 3.2777x over previous
//
#include <hip/hip_runtime.h>
#include <hip/hip_bf16.h>
#include <stdint.h>

#define DIM 1024
#define T_LEN 2048
#define NB 2
#define NH 16
#define HD 64
#define NQT 32   // 2048/64 q-tiles

typedef float f32x4 __attribute__((ext_vector_type(4)));
typedef float f32x16 __attribute__((ext_vector_type(16)));
typedef __bf16 bf16x8 __attribute__((ext_vector_type(8)));
typedef __bf16 bf16x2 __attribute__((ext_vector_type(2)));
typedef unsigned int u32;
typedef unsigned int u32x4 __attribute__((ext_vector_type(4)));

__device__ __forceinline__ float sgnf(float v) {
    return (v > 0.f) ? 1.f : ((v < 0.f) ? -1.f : 0.f);
}

__device__ __forceinline__ float sigmoid_half(float v) {
    // sigmoid(0.5*v) = 1/(1 + 2^(-0.5*log2(e)*v))
    return __builtin_amdgcn_rcpf(1.f + __builtin_amdgcn_exp2f(-0.72134752f * v));
}

__device__ __forceinline__ u32 pack2(float p0, float p1) {
    bf16x2 t = {(__bf16)p0, (__bf16)p1};
    return __builtin_bit_cast(u32, t);
}

// async global -> LDS, 16B per lane; LDS dest is wave-uniform base + lane*16
__device__ __forceinline__ void gload16(const __bf16* g, __bf16* l) {
    __builtin_amdgcn_global_load_lds(
        (__attribute__((address_space(1))) void*)g,
        (__attribute__((address_space(3))) void*)l,
        16, 0, 0);
}

// ---------------- prepass: x(f32) -> Xb (bf16 row-major), Xt (bf16, [b][h][d][t]) ----------------
__global__ __launch_bounds__(256) void prep_kernel(
    const float* __restrict__ x, __bf16* __restrict__ xb, __bf16* __restrict__ xt)
{
    __shared__ __align__(16) __bf16 tile[64][72];

    const int bid = blockIdx.x;
    const int h = bid & 15, tmp = bid >> 4, tt = tmp & 31, b = tmp >> 5;
    const int tid = threadIdx.x;
    const int r = tid >> 2, c0 = (tid & 3) * 16;

    const size_t rowbase = ((size_t)(b * T_LEN + tt * 64 + r)) * DIM + h * HD + c0;
    const float* xp = x + rowbase;

    __bf16 v[16];
    #pragma unroll
    for (int i = 0; i < 16; i += 4) {
        f32x4 f = *(const f32x4*)(xp + i);
        #pragma unroll
        for (int j = 0; j < 4; ++j) v[i + j] = (__bf16)f[j];
    }
    bf16x8 s0, s1;
    #pragma unroll
    for (int j = 0; j < 8; ++j) { s0[j] = v[j]; s1[j] = v[8 + j]; }
    *(bf16x8*)(xb + rowbase)     = s0;
    *(bf16x8*)(xb + rowbase + 8) = s1;
    *(bf16x8*)&tile[r][c0]     = s0;
    *(bf16x8*)&tile[r][c0 + 8] = s1;

    __syncthreads();

    const int d = tid >> 2, t0c = (tid & 3) * 16;
    __bf16 ov[16];
    #pragma unroll
    for (int i = 0; i < 16; ++i) ov[i] = tile[t0c + i][d];
    bf16x8 o0, o1;
    #pragma unroll
    for (int j = 0; j < 8; ++j) { o0[j] = ov[j]; o1[j] = ov[8 + j]; }
    const size_t obase = ((size_t)((b * NH + h) * HD + d)) * T_LEN + tt * 64 + t0c;
    *(bf16x8*)(xt + obase)     = o0;
    *(bf16x8*)(xt + obase + 8) = o1;
}

// ---------------- main: 32x32 MFMA, swapped QK^T, in-register P transpose ----------------
// QBLK=64 per block, 4 waves: wave w -> (q-half qh=w&1, s-half sh=w>>1).
// Each wave: S^T(32s x 32q) = mfma(K, Q); sigmoid; pack + 4x permlane32_swap
// assemble PV A-fragments in-register (no P LDS); O_partial(32q x 64d);
// epilogue reduces the two s-halves through LDS scratch aliased on the K ring.
// 3-deep K/V ring (48 KB) -> 3 blocks/CU; counted vmcnt(4) (4 loads/wave/tile).
__global__ __launch_bounds__(256, 3) void mba_main(
    const __bf16* __restrict__ xb, const __bf16* __restrict__ xt,
    const float* __restrict__ bvq, const float* __restrict__ bvk,
    const float* __restrict__ bvv, float* __restrict__ out)
{
    __shared__ __align__(16) __bf16 Kb[3][64][64];
    __shared__ __align__(16) __bf16 Vb[3][64][64];

    const int bid = blockIdx.x;
    const int qt = (NQT - 1) - (bid >> 5);   // heavy tiles dispatched first (LPT)
    const int bh = bid & 31;                 // low bits -> XCD locality on (b,h)
    const int b = bh >> 4, h = bh & 15;
    const int q0 = qt * 64;

    const int tid = threadIdx.x;
    const int w = tid >> 6, l = tid & 63;
    const int c = l & 31, hi = l >> 5;
    const int qh = w & 1, sh = w >> 1;

    const size_t xb_bh = (size_t)b * T_LEN * DIM + h * HD;      // row stride DIM
    const size_t xt_bh = (size_t)((b * NH + h) * HD) * T_LEN;   // row stride T_LEN

    // staging: lane covers (row = r0 + l>>3, granule = l&7); source granule
    // pre-swizzled by row&7 (involution; fragment reads apply the same XOR)
    const int rr = l >> 3;
    const int sw = ((l & 7) ^ rr) << 3;

    auto STAGE = [&](int buf, int kvt) {
        const int kv0 = kvt * 64;
        #pragma unroll
        for (int pt = 0; pt < 2; ++pt) {
            const int r0 = w * 8 + pt * 32;
            gload16(xb + xb_bh + (size_t)(kv0 + r0 + rr) * DIM + sw, &Kb[buf][r0][0]);
            gload16(xt + xt_bh + (size_t)(r0 + rr) * T_LEN + kv0 + sw, &Vb[buf][r0][0]);
        }
    };

    STAGE(0, 0);
    if (qt >= 1) STAGE(1, 1);

    // ---- Q fragments (B-operand): col=lane&31=q, k=(lane>>5)*8+j over 4 k-steps ----
    bf16x8 qa[4];
    {
        const float* bq = bvq + h * HD;
        const float* bk = bvk + h * HD;
        const int qrow = q0 + qh * 32 + c;
        #pragma unroll
        for (int m = 0; m < 4; ++m) {
            const int d0 = m * 16 + hi * 8;
            bf16x8 va = *(const bf16x8*)(xb + xb_bh + (size_t)qrow * DIM + d0);
            #pragma unroll
            for (int j = 0; j < 8; ++j) {
                float f = sgnf(bq[d0 + j]) * sgnf(bk[d0 + j]);
                qa[m][j] = (__bf16)((float)va[j] * f);
            }
        }
    }
    // V-sign for epilogue (column d = 32*nd + c)
    float sv[2];
    #pragma unroll
    for (int nd = 0; nd < 2; ++nd) sv[nd] = sgnf(bvv[h * HD + nd * 32 + c]);

    f32x16 o[2];
    #pragma unroll
    for (int nd = 0; nd < 2; ++nd)
        #pragma unroll
        for (int i = 0; i < 16; ++i) o[nd][i] = 0.f;

    int cur = 0;
    const int krow = sh * 32 + c;      // A-operand row for S^T (s index)
    const int swz = (c & 7) << 4;      // fragment-read deswizzle (row&7 == c&7)

    for (int t = 0; t <= qt; ++t) {
        const bool last = (t == qt);
        // counted drain: steady state has tiles {t, t+1} in flight (4 loads each,
        // per wave) -> vmcnt(4) retires exactly tile t. Last body drains all.
        if (last) { asm volatile("s_waitcnt vmcnt(0)" ::: "memory"); }
        else      { asm volatile("s_waitcnt vmcnt(4)" ::: "memory"); }
        __builtin_amdgcn_sched_barrier(0);
        __builtin_amdgcn_s_barrier();
        __builtin_amdgcn_sched_barrier(0);

        if (t + 2 <= qt) {             // recycled buf was fully read in body t-1
            int stg = cur + 2; if (stg >= 3) stg -= 3;
            STAGE(stg, t + 2);
        }

        // ---- S^T = K Q^T : D[s=(r&3)+8(r>>2)+4hi (+32sh)][q = qh*32+c] ----
        f32x16 ss;
        #pragma unroll
        for (int i = 0; i < 16; ++i) ss[i] = 0.f;
        #pragma unroll
        for (int m = 0; m < 4; ++m) {
            bf16x8 kf = *(const bf16x8*)((const char*)&Kb[cur][krow][0]
                          + ((m * 32 + hi * 16) ^ swz));
            ss = __builtin_amdgcn_mfma_f32_32x32x16_bf16(kf, qa[m], ss, 0, 0, 0);
        }

        // ---- sigmoid + causal mask -> 8 packed words (s-pairs, this lane's q) ----
        u32 W[8];
        #pragma unroll
        for (int i = 0; i < 8; ++i) {
            const int r0 = 2 * i;
            const int sl = (r0 & 3) + 8 * (r0 >> 2) + 4 * hi;   // s_loc of reg r0
            float p0 = sigmoid_half(ss[r0]);
            float p1 = sigmoid_half(ss[r0 + 1]);
            if (last) {
                const int sg = sh * 32 + sl;
                const int qg = qh * 32 + c;
                if (sg > qg)     p0 = 0.f;
                if (sg + 1 > qg) p1 = 0.f;
            }
            W[i] = pack2(p0, p1);
        }

        // ---- in-register transpose: 4x permlane32_swap assembles A-fragments ----
        // post-swap: pa0 = {W0,W1,W2,W3} covers s = 0..15, pa1 = {W4..W7} s = 16..31
        asm volatile("v_permlane32_swap_b32 %0, %1" : "+v"(W[0]), "+v"(W[2]));
        asm volatile("v_permlane32_swap_b32 %0, %1" : "+v"(W[1]), "+v"(W[3]));
        asm volatile("v_permlane32_swap_b32 %0, %1" : "+v"(W[4]), "+v"(W[6]));
        asm volatile("v_permlane32_swap_b32 %0, %1" : "+v"(W[5]), "+v"(W[7]));
        bf16x8 pa[2];
        pa[0] = __builtin_bit_cast(bf16x8, (u32x4){W[0], W[1], W[2], W[3]});
        pa[1] = __builtin_bit_cast(bf16x8, (u32x4){W[4], W[5], W[6], W[7]});

        // ---- O += P V : A=P (row=q, k=s), B=V rows of Vb (col=d, k=s) ----
        // BUGFIX (r5): V's s-dimension is the COLUMN of Vb[d][s], so the wave's
        // s-half offset sh*32 elements (sh*64 bytes) must be in the column
        // offset (K carries sh in its ROW instead). XOR after adding: the
        // swizzle permutes the full 3-bit granule index (byte bits 4..6).
        #pragma unroll
        for (int m = 0; m < 2; ++m) {
            #pragma unroll
            for (int nd = 0; nd < 2; ++nd) {
                bf16x8 vf = *(const bf16x8*)((const char*)&Vb[cur][nd * 32 + c][0]
                              + ((sh * 64 + m * 32 + hi * 16) ^ swz));
                o[nd] = __builtin_amdgcn_mfma_f32_32x32x16_bf16(pa[m], vf, o[nd], 0, 0, 0);
            }
        }
        cur = (cur == 2) ? 0 : cur + 1;
    }

    // ---- epilogue: reduce the two s-halves, apply sign(bvv), store ----
    __syncthreads();                               // all LDS ring reads/DMA done
    float (*osc)[64] = (float(*)[64]) & Kb[0][0][0];   // 16 KB scratch on K ring

    if (sh == 1) {
        #pragma unroll
        for (int r = 0; r < 16; ++r) {
            const int qloc = (r & 3) + 8 * (r >> 2) + 4 * hi;
            #pragma unroll
            for (int nd = 0; nd < 2; ++nd)
                osc[qh * 32 + qloc][nd * 32 + c] = o[nd][r];
        }
    }
    __syncthreads();
    if (sh == 0) {
        #pragma unroll
        for (int r = 0; r < 16; ++r) {
            const int qloc = (r & 3) + 8 * (r >> 2) + 4 * hi;
            const size_t row = (size_t)(b * T_LEN + q0 + qh * 32 + qloc) * DIM + h * HD;
            #pragma unroll
            for (int nd = 0; nd < 2; ++nd) {
                float val = (o[nd][r] + osc[qh * 32 + qloc][nd * 32 + c]) * sv[nd];
                out[row + nd * 32 + c] = val;
            }
        }
    }
}

// ---------------- fallback (round-1 kernel) if ws too small ----------------
__global__ __launch_bounds__(256) void mba_fallback(
    const float* __restrict__ x,
    const float* __restrict__ bvq,
    const float* __restrict__ bvk,
    const float* __restrict__ bvv,
    float* __restrict__ out)
{
    __shared__ __align__(16) __bf16 Kb[64][72];
    __shared__ __align__(16) __bf16 Vt[HD][72];
    __shared__ __align__(16) __bf16 Pb[4][16][72];

    const int bid = blockIdx.x;
    const int qt  = (NQT - 1) - (bid & (NQT - 1));
    const int bh  = bid >> 5;
    const int b   = bh >> 4;
    const int h   = bh & 15;

    const int tid = threadIdx.x;
    const int w   = tid >> 6;
    const int l   = tid & 63;
    const int lq  = l & 15;
    const int lh  = l >> 4;

    const int  q0    = qt * 64;
    const long xbase = ((long)b * T_LEN) * DIM + h * HD;

    bf16x8 qa[2];
    {
        const int   qrow = q0 + w * 16 + lq;
        const float* qp  = x + xbase + (long)qrow * DIM + lh * 8;
        const float* gp  = bvq + h * HD + lh * 8;
        #pragma unroll
        for (int ks = 0; ks < 2; ++ks)
            #pragma unroll
            for (int j = 0; j < 8; ++j)
                qa[ks][j] = (__bf16)(qp[ks * 32 + j] * sgnf(gp[ks * 32 + j]));
    }

    f32x4 o[4];
    #pragma unroll
    for (int n = 0; n < 4; ++n) o[n] = (f32x4){0.f, 0.f, 0.f, 0.f};

    const int r_st = tid >> 2;
    const int c0   = (tid & 3) * 16;
    const float* gk = bvk + h * HD + c0;
    const float* gv = bvv + h * HD + c0;

    for (int kvt = 0; kvt <= qt; ++kvt) {
        const int kv0 = kvt * 64;
        __syncthreads();
        {
            const float* kp = x + xbase + (long)(kv0 + r_st) * DIM + c0;
            __bf16 kb[16];
            #pragma unroll
            for (int i = 0; i < 16; ++i) kb[i] = (__bf16)(kp[i] * sgnf(gk[i]));
            *(bf16x8*)&Kb[r_st][c0]     = *(bf16x8*)&kb[0];
            *(bf16x8*)&Kb[r_st][c0 + 8] = *(bf16x8*)&kb[8];
            #pragma unroll
            for (int i = 0; i < 16; ++i)
                Vt[c0 + i][r_st] = (__bf16)(kp[i] * sgnf(gv[i]));
        }
        __syncthreads();

        f32x4 s[4];
        #pragma unroll
        for (int n = 0; n < 4; ++n) s[n] = (f32x4){0.f, 0.f, 0.f, 0.f};
        #pragma unroll
        for (int ks = 0; ks < 2; ++ks)
            #pragma unroll
            for (int n = 0; n < 4; ++n) {
                bf16x8 kf = *(const bf16x8*)&Kb[n * 16 + lq][ks * 32 + lh * 8];
                s[n] = __builtin_amdgcn_mfma_f32_16x16x32_bf16(qa[ks], kf, s[n], 0, 0, 0);
            }

        const bool diag = (kvt == qt);
        #pragma unroll
        for (int n = 0; n < 4; ++n)
            #pragma unroll
            for (int j = 0; j < 4; ++j) {
                float p = sigmoid_half(s[n][j]);
                if (diag && (n * 16 + lq) > (w * 16 + lh * 4 + j)) p = 0.f;
                Pb[w][lh * 4 + j][n * 16 + lq] = (__bf16)p;
            }

        #pragma unroll
        for (int ks = 0; ks < 2; ++ks) {
            bf16x8 pf = *(const bf16x8*)&Pb[w][lq][ks * 32 + lh * 8];
            #pragma unroll
            for (int n = 0; n < 4; ++n) {
                bf16x8 vf = *(const bf16x8*)&Vt[n * 16 + lq][ks * 32 + lh * 8];
                o[n] = __builtin_amdgcn_mfma_f32_16x16x32_bf16(pf, vf, o[n], 0, 0, 0);
            }
        }
    }

    float* op = out + ((long)b * T_LEN + q0 + w * 16) * DIM + h * HD;
    #pragma unroll
    for (int n = 0; n < 4; ++n)
        #pragma unroll
        for (int j = 0; j < 4; ++j)
            op[(long)(lh * 4 + j) * DIM + n * 16 + lq] = o[n][j];
}

extern "C" void kernel_launch(void* const* d_in, const int* in_sizes, int n_in,
                              void* d_out, int out_size, void* d_ws, size_t ws_size,
                              hipStream_t stream) {
    (void)in_sizes; (void)n_in; (void)out_size;
    const float* x   = (const float*)d_in[0];
    const float* bvq = (const float*)d_in[1];
    const float* bvk = (const float*)d_in[2];
    const float* bvv = (const float*)d_in[3];
    float* out = (float*)d_out;

    const size_t XB_BYTES = (size_t)NB * T_LEN * DIM * sizeof(__bf16);  // 8 MB
    const size_t XT_BYTES = XB_BYTES;                                    // 8 MB

    if (ws_size < XB_BYTES + XT_BYTES) {
        mba_fallback<<<NB * NH * NQT, 256, 0, stream>>>(x, bvq, bvk, bvv, out);
        return;
    }

    __bf16* xb = (__bf16*)d_ws;
    __bf16* xt = xb + (size_t)NB * T_LEN * DIM;

    prep_kernel<<<NB * NQT * NH, 256, 0, stream>>>(x, xb, xt);
    mba_main<<<NB * NH * NQT, 256, 0, stream>>>(xb, xt, bvq, bvk, bvv, out);
}

// Round 8
// 47.431 us; speedup vs baseline: 3.3028x; 1.0077x over previous
//
#include <hip/hip_runtime.h>
#include <hip/hip_bf16.h>
#include <stdint.h>

#define DIM 1024
#define T_LEN 2048
#define NB 2
#define NH 16
#define HD 64
#define NQT 32   // 2048/64 q-tiles

typedef float f32x4 __attribute__((ext_vector_type(4)));
typedef float f32x16 __attribute__((ext_vector_type(16)));
typedef __bf16 bf16x8 __attribute__((ext_vector_type(8)));
typedef __bf16 bf16x2 __attribute__((ext_vector_type(2)));
typedef unsigned int u32;
typedef unsigned int u32x4 __attribute__((ext_vector_type(4)));

__device__ __forceinline__ float sgnf(float v) {
    return (v > 0.f) ? 1.f : ((v < 0.f) ? -1.f : 0.f);
}

__device__ __forceinline__ float sigmoid_half(float v) {
    // sigmoid(0.5*v) = 1/(1 + 2^(-0.5*log2(e)*v))
    return __builtin_amdgcn_rcpf(1.f + __builtin_amdgcn_exp2f(-0.72134752f * v));
}

__device__ __forceinline__ u32 pack2(float p0, float p1) {
    bf16x2 t = {(__bf16)p0, (__bf16)p1};
    return __builtin_bit_cast(u32, t);
}

// async global -> LDS, 16B per lane; LDS dest is wave-uniform base + lane*16
__device__ __forceinline__ void gload16(const __bf16* g, __bf16* l) {
    __builtin_amdgcn_global_load_lds(
        (__attribute__((address_space(1))) void*)g,
        (__attribute__((address_space(3))) void*)l,
        16, 0, 0);
}

// ---------------- prepass: x(f32) -> Xb (bf16 row-major), Xt (bf16, [b][h][d][t]) ----------------
__global__ __launch_bounds__(256) void prep_kernel(
    const float* __restrict__ x, __bf16* __restrict__ xb, __bf16* __restrict__ xt)
{
    __shared__ __align__(16) __bf16 tile[64][72];

    const int bid = blockIdx.x;
    const int h = bid & 15, tmp = bid >> 4, tt = tmp & 31, b = tmp >> 5;
    const int tid = threadIdx.x;
    const int r = tid >> 2, c0 = (tid & 3) * 16;

    const size_t rowbase = ((size_t)(b * T_LEN + tt * 64 + r)) * DIM + h * HD + c0;
    const float* xp = x + rowbase;

    __bf16 v[16];
    #pragma unroll
    for (int i = 0; i < 16; i += 4) {
        f32x4 f = *(const f32x4*)(xp + i);
        #pragma unroll
        for (int j = 0; j < 4; ++j) v[i + j] = (__bf16)f[j];
    }
    bf16x8 s0, s1;
    #pragma unroll
    for (int j = 0; j < 8; ++j) { s0[j] = v[j]; s1[j] = v[8 + j]; }
    *(bf16x8*)(xb + rowbase)     = s0;
    *(bf16x8*)(xb + rowbase + 8) = s1;
    *(bf16x8*)&tile[r][c0]     = s0;
    *(bf16x8*)&tile[r][c0 + 8] = s1;

    __syncthreads();

    const int d = tid >> 2, t0c = (tid & 3) * 16;
    __bf16 ov[16];
    #pragma unroll
    for (int i = 0; i < 16; ++i) ov[i] = tile[t0c + i][d];
    bf16x8 o0, o1;
    #pragma unroll
    for (int j = 0; j < 8; ++j) { o0[j] = ov[j]; o1[j] = ov[8 + j]; }
    const size_t obase = ((size_t)((b * NH + h) * HD + d)) * T_LEN + tt * 64 + t0c;
    *(bf16x8*)(xt + obase)     = o0;
    *(bf16x8*)(xt + obase + 8) = o1;
}

// ---------------- main: 32x32 MFMA, K 3-ring + V 2-ring in LDS, 4 blocks/CU ----------------
// QBLK=64 per block, 4 waves: wave w -> (q-half qh=w&1, s-half sh=w>>1).
// Sync discipline (r6-proven): the explicit top-of-body wait ALONE guarantees
// tile-t K and V loads retired; correctness never depends on compiler waits.
// Issue order per body (pinned by sched_barrier): V(t+1)x2 then K(t+2)x2 ->
// invariant: at each body top only K_{t+1}x2 may remain in flight => steady
// wait vmcnt(2), last body vmcnt(0). LDS 40 KB -> 4 blocks/CU.
__global__ __launch_bounds__(256, 4) void mba_main(
    const __bf16* __restrict__ xb, const __bf16* __restrict__ xt,
    const float* __restrict__ bvq, const float* __restrict__ bvk,
    const float* __restrict__ bvv, float* __restrict__ out)
{
    __shared__ __align__(16) __bf16 Kb[3][64][64];   // 24 KB
    __shared__ __align__(16) __bf16 Vb[2][64][64];   // 16 KB

    const int bid = blockIdx.x;
    // balanced map: u in 0..31, jj=u>>3, aa=u&7 -> qt = 8jj + (jj odd ? 7-aa : aa)
    // (bijective; every CU's 4 resident blocks sum to exactly 66 bodies)
    const int u = bid >> 5;
    const int jj = u >> 3, aa = u & 7;
    const int qt = 8 * jj + ((jj & 1) ? (7 - aa) : aa);
    const int bh = bid & 31;                 // low bits -> XCD locality on (b,h)
    const int b = bh >> 4, h = bh & 15;
    const int q0 = qt * 64;

    const int tid = threadIdx.x;
    const int w = tid >> 6, l = tid & 63;
    const int c = l & 31, hi = l >> 5;
    const int qh = w & 1, sh = w >> 1;

    const size_t xb_bh = (size_t)b * T_LEN * DIM + h * HD;      // row stride DIM
    const size_t xt_bh = (size_t)((b * NH + h) * HD) * T_LEN;   // row stride T_LEN

    // staging: lane covers (row = r0 + l>>3, granule = l&7); source granule
    // pre-swizzled by row&7 (involution; fragment reads apply the same XOR)
    const int rr = l >> 3;
    const int sw = ((l & 7) ^ rr) << 3;

    auto STAGE_K = [&](int buf, int kvt) {   // 2 gload16 per wave
        const int kv0s = kvt * 64;
        #pragma unroll
        for (int pt = 0; pt < 2; ++pt) {
            const int r0 = w * 8 + pt * 32;
            gload16(xb + xb_bh + (size_t)(kv0s + r0 + rr) * DIM + sw, &Kb[buf][r0][0]);
        }
    };
    auto STAGE_V = [&](int buf, int kvt) {   // 2 gload16 per wave
        const int kv0s = kvt * 64;
        #pragma unroll
        for (int pt = 0; pt < 2; ++pt) {
            const int r0 = w * 8 + pt * 32;
            gload16(xt + xt_bh + (size_t)(r0 + rr) * T_LEN + kv0s + sw, &Vb[buf][r0][0]);
        }
    };

    // prologue order matters for the vmcnt invariant: K0, V0, then K1
    STAGE_K(0, 0);
    STAGE_V(0, 0);
    if (qt >= 1) STAGE_K(1, 1);

    // ---- Q fragments (B-operand): col=lane&31=q, k=(lane>>5)*8+j over 4 k-steps ----
    bf16x8 qa[4];
    {
        const float* bq = bvq + h * HD;
        const float* bk = bvk + h * HD;
        const int qrow = q0 + qh * 32 + c;
        #pragma unroll
        for (int m = 0; m < 4; ++m) {
            const int d0 = m * 16 + hi * 8;
            bf16x8 va = *(const bf16x8*)(xb + xb_bh + (size_t)qrow * DIM + d0);
            #pragma unroll
            for (int j = 0; j < 8; ++j) {
                float f = sgnf(bq[d0 + j]) * sgnf(bk[d0 + j]);
                qa[m][j] = (__bf16)((float)va[j] * f);
            }
        }
    }
    // V-sign for epilogue (column d = 32*nd + c)
    float sv[2];
    #pragma unroll
    for (int nd = 0; nd < 2; ++nd) sv[nd] = sgnf(bvv[h * HD + nd * 32 + c]);

    f32x16 o[2];
    #pragma unroll
    for (int nd = 0; nd < 2; ++nd)
        #pragma unroll
        for (int i = 0; i < 16; ++i) o[nd][i] = 0.f;

    int cur = 0;
    const int krow = sh * 32 + c;      // A-operand row for S^T (s index)
    const int swz = (c & 7) << 4;      // fragment-read deswizzle (row&7 == c&7)

    for (int t = 0; t <= qt; ++t) {
        const bool last = (t == qt);
        // SELF-SUFFICIENT wait: at body top, the only loads allowed to stay in
        // flight are K_{t+1}x2 (newest). vmcnt(2) retires K_t and V_t for this
        // wave; the barrier then makes all waves' tiles visible.
        if (last) { asm volatile("s_waitcnt vmcnt(0)" ::: "memory"); }
        else      { asm volatile("s_waitcnt vmcnt(2)" ::: "memory"); }
        __builtin_amdgcn_sched_barrier(0);
        __builtin_amdgcn_s_barrier();
        __builtin_amdgcn_sched_barrier(0);

        // ---- prefetch: V(t+1) FIRST, then K(t+2); order pinned ----
        if (t + 1 <= qt) STAGE_V((t + 1) & 1, t + 1);
        __builtin_amdgcn_sched_barrier(0);
        if (t + 2 <= qt) {             // recycled K buf was fully read in body t-1
            int stg = cur + 2; if (stg >= 3) stg -= 3;
            STAGE_K(stg, t + 2);
        }
        __builtin_amdgcn_sched_barrier(0);

        // ---- S^T = K Q^T : D[s=(r&3)+8(r>>2)+4hi (+32sh)][q = qh*32+c] ----
        f32x16 ss;
        #pragma unroll
        for (int i = 0; i < 16; ++i) ss[i] = 0.f;
        #pragma unroll
        for (int m = 0; m < 4; ++m) {
            bf16x8 kf = *(const bf16x8*)((const char*)&Kb[cur][krow][0]
                          + ((m * 32 + hi * 16) ^ swz));
            ss = __builtin_amdgcn_mfma_f32_32x32x16_bf16(kf, qa[m], ss, 0, 0, 0);
        }

        // ---- sigmoid + causal mask -> 8 packed words (s-pairs, this lane's q) ----
        u32 W[8];
        #pragma unroll
        for (int i = 0; i < 8; ++i) {
            const int r0 = 2 * i;
            const int sl = (r0 & 3) + 8 * (r0 >> 2) + 4 * hi;   // s_loc of reg r0
            float p0 = sigmoid_half(ss[r0]);
            float p1 = sigmoid_half(ss[r0 + 1]);
            if (last) {
                const int sg = sh * 32 + sl;
                const int qg = qh * 32 + c;
                if (sg > qg)     p0 = 0.f;
                if (sg + 1 > qg) p1 = 0.f;
            }
            W[i] = pack2(p0, p1);
        }

        // ---- in-register transpose: 4x permlane32_swap assembles A-fragments ----
        asm volatile("v_permlane32_swap_b32 %0, %1" : "+v"(W[0]), "+v"(W[2]));
        asm volatile("v_permlane32_swap_b32 %0, %1" : "+v"(W[1]), "+v"(W[3]));
        asm volatile("v_permlane32_swap_b32 %0, %1" : "+v"(W[4]), "+v"(W[6]));
        asm volatile("v_permlane32_swap_b32 %0, %1" : "+v"(W[5]), "+v"(W[7]));
        bf16x8 pa[2];
        pa[0] = __builtin_bit_cast(bf16x8, (u32x4){W[0], W[1], W[2], W[3]});
        pa[1] = __builtin_bit_cast(bf16x8, (u32x4){W[4], W[5], W[6], W[7]});

        // ---- O += P V : A=P (row=q, k=s), B=V rows of Vb (col=d, k=s) ----
        // V's s-dim is the COLUMN of Vb[d][s]: wave's s-half offset sh*64 bytes
        // lives in the column offset (K carries sh in its ROW instead).
        #pragma unroll
        for (int m = 0; m < 2; ++m) {
            #pragma unroll
            for (int nd = 0; nd < 2; ++nd) {
                bf16x8 vf = *(const bf16x8*)((const char*)&Vb[t & 1][nd * 32 + c][0]
                              + ((sh * 64 + m * 32 + hi * 16) ^ swz));
                o[nd] = __builtin_amdgcn_mfma_f32_32x32x16_bf16(pa[m], vf, o[nd], 0, 0, 0);
            }
        }
        cur = (cur == 2) ? 0 : cur + 1;
    }

    // ---- epilogue: reduce the two s-halves, apply sign(bvv), store ----
    __syncthreads();                               // all LDS ring reads/DMA done
    float (*osc)[64] = (float(*)[64]) & Kb[0][0][0];   // 16 KB scratch on K ring

    if (sh == 1) {
        #pragma unroll
        for (int r = 0; r < 16; ++r) {
            const int qloc = (r & 3) + 8 * (r >> 2) + 4 * hi;
            #pragma unroll
            for (int nd = 0; nd < 2; ++nd)
                osc[qh * 32 + qloc][nd * 32 + c] = o[nd][r];
        }
    }
    __syncthreads();
    if (sh == 0) {
        #pragma unroll
        for (int r = 0; r < 16; ++r) {
            const int qloc = (r & 3) + 8 * (r >> 2) + 4 * hi;
            const size_t row = (size_t)(b * T_LEN + q0 + qh * 32 + qloc) * DIM + h * HD;
            #pragma unroll
            for (int nd = 0; nd < 2; ++nd) {
                float val = (o[nd][r] + osc[qh * 32 + qloc][nd * 32 + c]) * sv[nd];
                out[row + nd * 32 + c] = val;
            }
        }
    }
}

// ---------------- fallback (round-1 kernel) if ws too small ----------------
__global__ __launch_bounds__(256) void mba_fallback(
    const float* __restrict__ x,
    const float* __restrict__ bvq,
    const float* __restrict__ bvk,
    const float* __restrict__ bvv,
    float* __restrict__ out)
{
    __shared__ __align__(16) __bf16 Kb[64][72];
    __shared__ __align__(16) __bf16 Vt[HD][72];
    __shared__ __align__(16) __bf16 Pb[4][16][72];

    const int bid = blockIdx.x;
    const int qt  = (NQT - 1) - (bid & (NQT - 1));
    const int bh  = bid >> 5;
    const int b   = bh >> 4;
    const int h   = bh & 15;

    const int tid = threadIdx.x;
    const int w   = tid >> 6;
    const int l   = tid & 63;
    const int lq  = l & 15;
    const int lh  = l >> 4;

    const int  q0    = qt * 64;
    const long xbase = ((long)b * T_LEN) * DIM + h * HD;

    bf16x8 qa[2];
    {
        const int   qrow = q0 + w * 16 + lq;
        const float* qp  = x + xbase + (long)qrow * DIM + lh * 8;
        const float* gp  = bvq + h * HD + lh * 8;
        #pragma unroll
        for (int ks = 0; ks < 2; ++ks)
            #pragma unroll
            for (int j = 0; j < 8; ++j)
                qa[ks][j] = (__bf16)(qp[ks * 32 + j] * sgnf(gp[ks * 32 + j]));
    }

    f32x4 o[4];
    #pragma unroll
    for (int n = 0; n < 4; ++n) o[n] = (f32x4){0.f, 0.f, 0.f, 0.f};

    const int r_st = tid >> 2;
    const int c0   = (tid & 3) * 16;
    const float* gk = bvk + h * HD + c0;
    const float* gv = bvv + h * HD + c0;

    for (int kvt = 0; kvt <= qt; ++kvt) {
        const int kv0 = kvt * 64;
        __syncthreads();
        {
            const float* kp = x + xbase + (long)(kv0 + r_st) * DIM + c0;
            __bf16 kb[16];
            #pragma unroll
            for (int i = 0; i < 16; ++i) kb[i] = (__bf16)(kp[i] * sgnf(gk[i]));
            *(bf16x8*)&Kb[r_st][c0]     = *(bf16x8*)&kb[0];
            *(bf16x8*)&Kb[r_st][c0 + 8] = *(bf16x8*)&kb[8];
            #pragma unroll
            for (int i = 0; i < 16; ++i)
                Vt[c0 + i][r_st] = (__bf16)(kp[i] * sgnf(gv[i]));
        }
        __syncthreads();

        f32x4 s[4];
        #pragma unroll
        for (int n = 0; n < 4; ++n) s[n] = (f32x4){0.f, 0.f, 0.f, 0.f};
        #pragma unroll
        for (int ks = 0; ks < 2; ++ks)
            #pragma unroll
            for (int n = 0; n < 4; ++n) {
                bf16x8 kf = *(const bf16x8*)&Kb[n * 16 + lq][ks * 32 + lh * 8];
                s[n] = __builtin_amdgcn_mfma_f32_16x16x32_bf16(qa[ks], kf, s[n], 0, 0, 0);
            }

        const bool diag = (kvt == qt);
        #pragma unroll
        for (int n = 0; n < 4; ++n)
            #pragma unroll
            for (int j = 0; j < 4; ++j) {
                float p = sigmoid_half(s[n][j]);
                if (diag && (n * 16 + lq) > (w * 16 + lh * 4 + j)) p = 0.f;
                Pb[w][lh * 4 + j][n * 16 + lq] = (__bf16)p;
            }

        #pragma unroll
        for (int ks = 0; ks < 2; ++ks) {
            bf16x8 pf = *(const bf16x8*)&Pb[w][lq][ks * 32 + lh * 8];
            #pragma unroll
            for (int n = 0; n < 4; ++n) {
                bf16x8 vf = *(const bf16x8*)&Vt[n * 16 + lq][ks * 32 + lh * 8];
                o[n] = __builtin_amdgcn_mfma_f32_16x16x32_bf16(pf, vf, o[n], 0, 0, 0);
            }
        }
    }

    float* op = out + ((long)b * T_LEN + q0 + w * 16) * DIM + h * HD;
    #pragma unroll
    for (int n = 0; n < 4; ++n)
        #pragma unroll
        for (int j = 0; j < 4; ++j)
            op[(long)(lh * 4 + j) * DIM + n * 16 + lq] = o[n][j];
}

extern "C" void kernel_launch(void* const* d_in, const int* in_sizes, int n_in,
                              void* d_out, int out_size, void* d_ws, size_t ws_size,
                              hipStream_t stream) {
    (void)in_sizes; (void)n_in; (void)out_size;
    const float* x   = (const float*)d_in[0];
    const float* bvq = (const float*)d_in[1];
    const float* bvk = (const float*)d_in[2];
    const float* bvv = (const float*)d_in[3];
    float* out = (float*)d_out;

    const size_t XB_BYTES = (size_t)NB * T_LEN * DIM * sizeof(__bf16);  // 8 MB
    const size_t XT_BYTES = XB_BYTES;                                    // 8 MB

    if (ws_size < XB_BYTES + XT_BYTES) {
        mba_fallback<<<NB * NH * NQT, 256, 0, stream>>>(x, bvq, bvk, bvv, out);
        return;
    }

    __bf16* xb = (__bf16*)d_ws;
    __bf16* xt = xb + (size_t)NB * T_LEN * DIM;

    prep_kernel<<<NB * NQT * NH, 256, 0, stream>>>(x, xb, xt);
    mba_main<<<NB * NH * NQT, 256, 0, stream>>>(xb, xt, bvq, bvk, bvv, out);
}